// Round 5
// baseline (268.322 us; speedup 1.0000x reference)
//
#include <hip/hip_runtime.h>
#include <math.h>
#include <stdint.h>

// excess[b,m] = K·T + SIGMA*e*(T^4 - Tenv^4) - (H+F);  out = mean(|excess|)
// K = 5-band stencil on a 13x13 grid; GLx = -K[1][2]; GR = e_diag[1];
// interface nodes {0,12,156,168} are identity rows with e=0.
//
// v9: persistent blocks + double-buffered LDS staging (T3 2-phase pipeline).
// Diagnosis from v4-v8: the op is concurrency-bound (one-shot waves keep loads
// in flight only during their stall window; ~5 KB/CU effective -> 4.2 TB/s
// demand ceiling). Fix: 768 persistent blocks (3/CU, LDS-limited), each owns
// ~14 contiguous 2048-elem tiles; tile t+1 is staged into the spare LDS buffer
// via global_load_lds (width 16) BEFORE computing tile t, so the vmcnt(0)
// drain at the barrier is ~free and ~75 KB/CU stays in flight continuously.
// Compute = v7's validated mask-table math; neighbors come from the staged
// tile (halo +-16): no shuffles, no fringe loads, no fast/slow split. Halo
// entries mapping to global index <0 or >=total are clamped loads whose
// values are exactly the geometry-masked (m<13 / m>=156) set.

#define SIGMA_F 5.67e-8f

constexpr int BLOCK = 256;
constexpr int TILE  = 2048;               // elements per tile (8 per thread)
constexpr int THALO = 16;
constexpr int TWIN  = TILE + 2 * THALO;   // 2080 floats of T staged

typedef float f4b __attribute__((ext_vector_type(4), aligned(16)));

static __device__ __forceinline__ void gl_lds16(const float* g, float* l) {
    __builtin_amdgcn_global_load_lds(
        (const __attribute__((address_space(1))) void*)g,
        (__attribute__((address_space(3))) void*)l, 16, 0, 0);
}

__global__ __launch_bounds__(256) void fused_residual_v9(
    const float* __restrict__ T,      // [B*169]
    const float* __restrict__ H,
    const float* __restrict__ F,
    const float* __restrict__ Tenv,   // [B]
    const float* __restrict__ K,      // [169*169]
    const float* __restrict__ Ediag,  // [169]
    float* __restrict__ partials,
    int total,                        // B*169
    int ntiles)                       // total / TILE
{
    __shared__ float sT[2][TWIN];
    __shared__ float sH[2][TILE];
    __shared__ float sF[2][TILE];
    __shared__ unsigned sTab[184];
    __shared__ float sred[BLOCK / 64];

    const float GLx = -K[1 * 169 + 2];     // interior coupling (dx==dy)
    const float GRs = SIGMA_F * Ediag[1];  // sigma * GR
    const int tid = (int)threadIdx.x;

    // per-m neighbor-mask table (736 B); padded so m0+j needs no mod
    if (tid < 184) {
        int m = (tid < 169) ? tid : tid - 169;
        int ii = m % 13;
        unsigned cW = (ii > 0)  ? 1u : 0u;
        unsigned cE = (ii < 12) ? 1u : 0u;
        unsigned cN = (m < 156) ? 1u : 0u;
        unsigned cS = (m >= 13) ? 1u : 0u;
        sTab[tid] = cW | (cE << 8) | (cN << 16) | (cS << 24);
    }

    // static contiguous tile partition across blocks
    const int nb  = (int)gridDim.x;
    const int bid = (int)blockIdx.x;
    const int qd  = ntiles / nb, rem = ntiles % nb;
    const int t0  = bid * qd + (bid < rem ? bid : rem);
    const int nt  = qd + (bid < rem ? 1 : 0);

    float acc = 0.0f;

    auto STAGE = [&](int buf, int tile) {
        const int gb = tile * TILE;
        #pragma unroll
        for (int k = 0; k < 3; ++k) {           // T window incl. halo (2080 fl)
            const int c = tid + k * BLOCK;      // 16B chunk id
            if (c < TWIN / 4) {
                int src = gb - THALO + c * 4;   // clamp: tile0 front / last back
                src = src < 0 ? 0 : src;
                src = src > total - 4 ? total - 4 : src;
                gl_lds16(T + src, &sT[buf][c * 4]);
            }
        }
        #pragma unroll
        for (int k = 0; k < 2; ++k) {           // H and F (2048 fl each)
            const int c = tid + k * BLOCK;
            gl_lds16(H + gb + c * 4, &sH[buf][c * 4]);
            gl_lds16(F + gb + c * 4, &sF[buf][c * 4]);
        }
    };

    if (nt > 0) {
        STAGE(0, t0);
        __syncthreads();                        // drains stage(t0) + table init
        int cur = 0;
        for (int k = 0; k < nt; ++k) {
            if (k + 1 < nt) STAGE(cur ^ 1, t0 + k + 1);   // prefetch next tile

            const int tb = (t0 + k) * TILE;
            const int e0 = tb + tid * 8;
            const int lb = THALO + tid * 8;
            const float* __restrict__ Tb = &sT[cur][0];

            // own row (16B-aligned), neighbors at +-13, +-1 from staged tile
            f4b a0 = *(const f4b*)&Tb[lb];
            f4b a1 = *(const f4b*)&Tb[lb + 4];
            float s0 = Tb[lb - 13];
            f4b sA = *(const f4b*)&Tb[lb - 12];   // byte 32t+16: aligned
            f4b sB = *(const f4b*)&Tb[lb - 8];    // byte 32t+32: aligned
            float n0 = Tb[lb + 13], n1 = Tb[lb + 14], n2 = Tb[lb + 15];
            f4b nA = *(const f4b*)&Tb[lb + 16];   // byte 32t+128: aligned
            float n7 = Tb[lb + 20];
            float tw = Tb[lb - 1], te = Tb[lb + 8];
            f4b h0v = *(const f4b*)&sH[cur][tid * 8];
            f4b h1v = *(const f4b*)&sH[cur][tid * 8 + 4];
            f4b f0v = *(const f4b*)&sF[cur][tid * 8];
            f4b f1v = *(const f4b*)&sF[cur][tid * 8 + 4];

            const float tC[8] = {a0.x, a0.y, a0.z, a0.w, a1.x, a1.y, a1.z, a1.w};
            const float sv[8] = {s0, sA.x, sA.y, sA.z, sA.w, sB.x, sB.y, sB.z};
            const float nv[8] = {n0, n1, n2, nA.x, nA.y, nA.z, nA.w, n7};
            const float qv[8] = {h0v.x + f0v.x, h0v.y + f0v.y,
                                 h0v.z + f0v.z, h0v.w + f0v.w,
                                 h1v.x + f1v.x, h1v.y + f1v.y,
                                 h1v.z + f1v.z, h1v.w + f1v.w};

            const unsigned ue = (unsigned)e0;
            const unsigned b0 = ue / 169u;         // magic-mul
            const int m0 = (int)(ue - b0 * 169u);

            float tvA = Tenv[b0];
            float tvB = tvA;
            if (m0 >= 162) tvB = Tenv[b0 + 1];     // 8-group crosses batch edge
            const float tv4A = (tvA * tvA) * (tvA * tvA);
            const float tv4B = (tvB * tvB) * (tvB * tvB);

            #pragma unroll
            for (int j = 0; j < 8; ++j) {
                const unsigned w = sTab[m0 + j];            // padded: no mod
                const float mW = (float)(w & 0xffu);        // v_cvt_f32_ubyte*
                const float mE = (float)((w >> 8) & 0xffu);
                const float mN = (float)((w >> 16) & 0xffu);
                const float mS = (float)(w >> 24);

                const float t  = tC[j];
                const float twv = (j == 0) ? tw : tC[j - 1];
                const float tev = (j == 7) ? te : tC[j + 1];
                float s = mW * twv;
                s = fmaf(mE, tev, s);
                s = fmaf(mN, nv[j], s);
                s = fmaf(mS, sv[j], s);
                const float nn = (mW + mE) + (mN + mS);
                const float q  = qv[j];
                const float tv4 = (m0 + j >= 169) ? tv4B : tv4A;
                const float t2 = t * t;
                const float d  = fmaf(t2, t2, -tv4);        // t^4 - tv^4
                const float core = fmaf(GLx, fmaf(nn, t, -s), fmaf(GRs, d, -q));
                const float ex = (nn == 2.0f) ? (t - q) : core;  // corners
                acc += fabsf(ex);
            }

            __syncthreads();     // readers done with cur^1; stage(k+1) drained
            cur ^= 1;
        }
    }

    // leftover elements if total % TILE != 0 (never for the bench size)
    for (int e = ntiles * TILE + bid * BLOCK + tid; e < total;
         e += nb * BLOCK) {
        unsigned b = (unsigned)e / 169u;
        int m = e - (int)b * 169;
        int ii = m % 13;
        bool cE = (ii < 12), cW = (ii > 0), cN = (m < 156), cS = (m >= 13);
        bool ifc = (m == 0) | (m == 12) | (m == 156) | (m == 168);
        float t  = T[e];
        float s  = (cE ? T[e + 1] : 0.0f) + (cW ? T[e - 1] : 0.0f)
                 + (cN ? T[e + 13] : 0.0f) + (cS ? T[e - 13] : 0.0f);
        float nn = (float)((int)cE + (int)cW + (int)cN + (int)cS);
        float tv = Tenv[b];
        float tv4 = (tv * tv) * (tv * tv);
        float t2 = t * t, t4 = t2 * t2;
        float qq = H[e] + F[e];
        float ex = ifc ? (t - qq) : (GLx * (nn * t - s) + GRs * (t4 - tv4) - qq);
        acc += fabsf(ex);
    }

    #pragma unroll
    for (int off = 32; off > 0; off >>= 1)
        acc += __shfl_down(acc, off, 64);
    const int lane = tid & 63;
    const int wid  = tid >> 6;
    if (lane == 0) sred[wid] = acc;
    __syncthreads();
    if (tid == 0) {
        float s = 0.0f;
        #pragma unroll
        for (int w = 0; w < BLOCK / 64; ++w) s += sred[w];
        partials[bid] = s;
    }
}

__global__ __launch_bounds__(256) void finalize_kernel(
    const float* __restrict__ partials, int n,
    float* __restrict__ out, float inv_total)
{
    __shared__ float sred[BLOCK / 64];
    float acc = 0.0f;
    for (int i = (int)threadIdx.x; i < n; i += BLOCK) acc += partials[i];
    #pragma unroll
    for (int off = 32; off > 0; off >>= 1)
        acc += __shfl_down(acc, off, 64);
    int lane = threadIdx.x & 63;
    int wid  = threadIdx.x >> 6;
    if (lane == 0) sred[wid] = acc;
    __syncthreads();
    if (threadIdx.x == 0) {
        float s = 0.0f;
        #pragma unroll
        for (int w = 0; w < BLOCK / 64; ++w) s += sred[w];
        out[0] = s * inv_total;
    }
}

extern "C" void kernel_launch(void* const* d_in, const int* in_sizes, int n_in,
                              void* d_out, int out_size, void* d_ws, size_t ws_size,
                              hipStream_t stream) {
    const float* T    = (const float*)d_in[0];
    const float* H    = (const float*)d_in[1];
    const float* F    = (const float*)d_in[2];
    const float* Tenv = (const float*)d_in[3];
    const float* K    = (const float*)d_in[4];
    const float* E    = (const float*)d_in[5];
    float* out      = (float*)d_out;
    float* partials = (float*)d_ws;

    const int total  = in_sizes[0];            // B * 169
    const int ntiles = total / TILE;           // 10816 for B=131072

    // Persistent grid: 3 blocks/CU (LDS-limited) x 256 CUs.
    int grid = 768;
    if (grid > ntiles) grid = ntiles > 0 ? ntiles : 1;
    if ((size_t)grid * sizeof(float) > ws_size) grid = (int)(ws_size / sizeof(float));
    if (grid < 1) grid = 1;

    fused_residual_v9<<<grid, BLOCK, 0, stream>>>(T, H, F, Tenv, K, E, partials,
                                                  total, ntiles);

    const float inv_total = 1.0f / (float)total;
    finalize_kernel<<<1, BLOCK, 0, stream>>>(partials, grid, out, inv_total);
}

// Round 6
// 243.222 us; speedup vs baseline: 1.1032x; 1.1032x over previous
//
#include <hip/hip_runtime.h>
#include <math.h>

// excess[b,m] = K·T + SIGMA*e*(T^4 - Tenv^4) - (H+F);  out = mean(|excess|)
// K = 5-band stencil on a 13x13 grid; GLx = -K[1][2]; GR = e_diag[1];
// interface nodes {0,12,156,168} are identity rows with e=0.
//
// v10 = v7's barrier-free body + per-wave register pipelining.
// Diagnosis (v4-v9): duration tracks occupancy x load-issue duty cycle;
// barrier/LDS pipelines (v6,v9) pay occupancy+drain, one-shot waves (v4,v7)
// idle their load pipe ~2/3 of the time. Fix: grid=2048 persistent-ish
// blocks (~5.3 iters/thread), and each iteration ISSUES the next iteration's
// 6 dwordx4 into a second register buffer BEFORE computing the current one.
// The vmcnt wait lands at the buffer swap after compute -> loads stay in
// flight under the whole compute phase. No barriers, no LDS staging.

#define SIGMA_F 5.67e-8f

constexpr int BLOCK = 256;

typedef float f4a __attribute__((ext_vector_type(4), aligned(4)));   // unaligned x4
typedef float f4b __attribute__((ext_vector_type(4), aligned(16)));  // aligned x4

__global__ __launch_bounds__(256) void fused_residual_v10(
    const float* __restrict__ T,      // [B*169]
    const float* __restrict__ H,
    const float* __restrict__ F,
    const float* __restrict__ Tenv,   // [B]
    const float* __restrict__ K,      // [169*169]
    const float* __restrict__ Ediag,  // [169]
    float* __restrict__ partials,
    int total)
{
    __shared__ unsigned sTab[184];
    __shared__ float sred[BLOCK / 64];

    const float GLx = -K[1 * 169 + 2];     // interior coupling (dx==dy -> GLx==GLy)
    const float GRs = SIGMA_F * Ediag[1];  // sigma * GR

    const int tid  = (int)threadIdx.x;
    const int lane = tid & 63;

    // per-m neighbor-mask table (736 B); padded so m0+j needs no mod
    if (tid < 184) {
        int m = (tid < 169) ? tid : tid - 169;
        int ii = m % 13;
        unsigned cW = (ii > 0)  ? 1u : 0u;
        unsigned cE = (ii < 12) ? 1u : 0u;
        unsigned cN = (m < 156) ? 1u : 0u;
        unsigned cS = (m >= 13) ? 1u : 0u;
        sTab[tid] = cW | (cE << 8) | (cN << 16) | (cS << 24);
    }
    __syncthreads();

    float acc = 0.0f;

    const int gstride = gridDim.x * BLOCK;

    // wave-uniform fast test: whole wave's 512-elem window + halo in bounds
    auto isfast = [&](int gg) -> bool {
        const int wb = gg * 8 - lane * 8;          // wave base (uniform)
        return (wb >= 16) && (wb + 64 * 8 + 16 <= total);
    };

    int  g        = (int)blockIdx.x * BLOCK + tid;
    bool haveCur  = (g * 8 < total);
    bool fastCur  = haveCur && isfast(g);

    f4b ct0, ct1, ch0, ch1, cf0, cf1;              // current buffer
    if (fastCur) {
        const int e0 = g * 8;
        ct0 = *(const f4b*)(T + e0);
        ct1 = *(const f4b*)(T + e0 + 4);
        ch0 = __builtin_nontemporal_load((const f4b*)(H + e0));
        ch1 = __builtin_nontemporal_load((const f4b*)(H + e0 + 4));
        cf0 = __builtin_nontemporal_load((const f4b*)(F + e0));
        cf1 = __builtin_nontemporal_load((const f4b*)(F + e0 + 4));
    }

    while (haveCur) {
        const int  gn    = g + gstride;
        const bool haveN = (gn * 8 < total);
        const bool fastN = haveN && isfast(gn);

        // ---- prefetch next iteration (issued BEFORE current compute) ----
        f4b pt0, pt1, ph0, ph1, pf0, pf1;
        if (fastN) {
            const int en = gn * 8;
            pt0 = *(const f4b*)(T + en);
            pt1 = *(const f4b*)(T + en + 4);
            ph0 = __builtin_nontemporal_load((const f4b*)(H + en));
            ph1 = __builtin_nontemporal_load((const f4b*)(H + en + 4));
            pf0 = __builtin_nontemporal_load((const f4b*)(F + en));
            pf1 = __builtin_nontemporal_load((const f4b*)(F + en + 4));
        }
        __builtin_amdgcn_sched_barrier(0);   // keep prefetch issue above compute

        // ---- compute current iteration ----
        if (fastCur) {
            const int e0 = g * 8;

            // South: value at local idx 8*lane + j - 13
            float sv[8];
            sv[0] = __shfl_up(ct0.w, 2);
            sv[1] = __shfl_up(ct1.x, 2);
            sv[2] = __shfl_up(ct1.y, 2);
            sv[3] = __shfl_up(ct1.z, 2);
            sv[4] = __shfl_up(ct1.w, 2);
            sv[5] = __shfl_up(ct0.x, 1);
            sv[6] = __shfl_up(ct0.y, 1);
            sv[7] = __shfl_up(ct0.z, 1);
            if (lane < 2) {                       // fringe below wave window
                f4a a = *(const f4a*)(T + e0 - 13);
                f4a b = *(const f4a*)(T + e0 - 9);
                sv[0] = a.x; sv[1] = a.y; sv[2] = a.z; sv[3] = a.w;
                sv[4] = b.x; sv[5] = b.y; sv[6] = b.z; sv[7] = b.w;
            }
            // North: value at local idx 8*lane + j + 13
            float nv[8];
            nv[0] = __shfl_down(ct1.y, 1);
            nv[1] = __shfl_down(ct1.z, 1);
            nv[2] = __shfl_down(ct1.w, 1);
            nv[3] = __shfl_down(ct0.x, 2);
            nv[4] = __shfl_down(ct0.y, 2);
            nv[5] = __shfl_down(ct0.z, 2);
            nv[6] = __shfl_down(ct0.w, 2);
            nv[7] = __shfl_down(ct1.x, 2);
            if (lane >= 62) {                     // fringe above wave window
                f4a a = *(const f4a*)(T + e0 + 13);
                f4a b = *(const f4a*)(T + e0 + 17);
                nv[0] = a.x; nv[1] = a.y; nv[2] = a.z; nv[3] = a.w;
                nv[4] = b.x; nv[5] = b.y; nv[6] = b.z; nv[7] = b.w;
            }
            // West / East chunk edges
            float left = __shfl_up(ct1.w, 1);
            if (lane == 0) left = T[e0 - 1];
            float right = __shfl_down(ct0.x, 1);
            if (lane == 63) right = T[e0 + 8];

            const unsigned ue = (unsigned)e0;
            const unsigned b0 = ue / 169u;        // magic-mul
            const int m0 = (int)(ue - b0 * 169u);

            float tvA = Tenv[b0];
            float tvB = tvA;
            if (m0 >= 162) tvB = Tenv[b0 + 1];    // 8-group crosses batch boundary
            const float tv4A = (tvA * tvA) * (tvA * tvA);
            const float tv4B = (tvB * tvB) * (tvB * tvB);

            const float tCv[8] = {ct0.x, ct0.y, ct0.z, ct0.w,
                                  ct1.x, ct1.y, ct1.z, ct1.w};
            const float tWv[8] = {left, ct0.x, ct0.y, ct0.z,
                                  ct0.w, ct1.x, ct1.y, ct1.z};
            const float tEv[8] = {ct0.y, ct0.z, ct0.w, ct1.x,
                                  ct1.y, ct1.z, ct1.w, right};
            const float hq[8]  = {ch0.x + cf0.x, ch0.y + cf0.y,
                                  ch0.z + cf0.z, ch0.w + cf0.w,
                                  ch1.x + cf1.x, ch1.y + cf1.y,
                                  ch1.z + cf1.z, ch1.w + cf1.w};

            #pragma unroll
            for (int j = 0; j < 8; ++j) {
                const unsigned w = sTab[m0 + j];            // padded: no mod
                const float mW = (float)(w & 0xffu);        // v_cvt_f32_ubyte0..3
                const float mE = (float)((w >> 8) & 0xffu);
                const float mN = (float)((w >> 16) & 0xffu);
                const float mS = (float)(w >> 24);

                const float t = tCv[j];
                float s = mW * tWv[j];
                s = fmaf(mE, tEv[j], s);
                s = fmaf(mN, nv[j], s);
                s = fmaf(mS, sv[j], s);
                const float nn = (mW + mE) + (mN + mS);
                const float q  = hq[j];
                const float tv4 = (m0 + j >= 169) ? tv4B : tv4A;
                const float t2 = t * t;
                const float d  = fmaf(t2, t2, -tv4);        // t^4 - tv^4
                const float core = fmaf(GLx, fmaf(nn, t, -s), fmaf(GRs, d, -q));
                const float ex = (nn == 2.0f) ? (t - q) : core;  // interface=corner
                acc += fabsf(ex);
            }
        } else {
            // boundary waves (first/last of the grid): scalar, exact, in-bounds
            const int e0 = g * 8;
            #pragma unroll
            for (int j = 0; j < 8; ++j) {
                int e = e0 + j;
                if (e >= total) break;
                unsigned b = (unsigned)e / 169u;
                int m = e - (int)b * 169;
                unsigned q13 = (unsigned)m / 13u;
                int ii = m - (int)q13 * 13;
                bool cE = (ii < 12), cW = (ii > 0), cN = (m < 156), cS = (m >= 13);
                bool ifc = (m == 0) | (m == 12) | (m == 156) | (m == 168);
                float t  = T[e];
                float tEv2 = cE ? T[e + 1]  : 0.0f;
                float tWv2 = cW ? T[e - 1]  : 0.0f;
                float tNv2 = cN ? T[e + 13] : 0.0f;
                float tSv2 = cS ? T[e - 13] : 0.0f;
                float s  = tEv2 + tWv2 + tNv2 + tSv2;
                float nn = (float)((int)cE + (int)cW + (int)cN + (int)cS);
                float tv = Tenv[b];
                float tv4 = (tv * tv) * (tv * tv);
                float t2 = t * t, t4 = t2 * t2;
                float qq = H[e] + F[e];
                float ex = ifc ? (t - qq)
                               : (GLx * (nn * t - s) + GRs * (t4 - tv4) - qq);
                acc += fabsf(ex);
            }
        }

        // ---- swap: vmcnt wait for the prefetched regs lands HERE ----
        ct0 = pt0; ct1 = pt1; ch0 = ph0; ch1 = ph1; cf0 = pf0; cf1 = pf1;
        fastCur = fastN;
        haveCur = haveN;
        g = gn;
    }

    #pragma unroll
    for (int off = 32; off > 0; off >>= 1)
        acc += __shfl_down(acc, off, 64);
    const int wid = tid >> 6;
    if (lane == 0) sred[wid] = acc;
    __syncthreads();
    if (tid == 0) {
        float s = 0.0f;
        #pragma unroll
        for (int w = 0; w < BLOCK / 64; ++w) s += sred[w];
        partials[blockIdx.x] = s;
    }
}

__global__ __launch_bounds__(256) void finalize_kernel(
    const float* __restrict__ partials, int n,
    float* __restrict__ out, float inv_total)
{
    __shared__ float sred[BLOCK / 64];
    float acc = 0.0f;
    for (int i = (int)threadIdx.x; i < n; i += BLOCK) acc += partials[i];
    #pragma unroll
    for (int off = 32; off > 0; off >>= 1)
        acc += __shfl_down(acc, off, 64);
    int lane = threadIdx.x & 63;
    int wid  = threadIdx.x >> 6;
    if (lane == 0) sred[wid] = acc;
    __syncthreads();
    if (threadIdx.x == 0) {
        float s = 0.0f;
        #pragma unroll
        for (int w = 0; w < BLOCK / 64; ++w) s += sred[w];
        out[0] = s * inv_total;
    }
}

extern "C" void kernel_launch(void* const* d_in, const int* in_sizes, int n_in,
                              void* d_out, int out_size, void* d_ws, size_t ws_size,
                              hipStream_t stream) {
    const float* T    = (const float*)d_in[0];
    const float* H    = (const float*)d_in[1];
    const float* F    = (const float*)d_in[2];
    const float* Tenv = (const float*)d_in[3];
    const float* K    = (const float*)d_in[4];
    const float* E    = (const float*)d_in[5];
    float* out      = (float*)d_out;
    float* partials = (float*)d_ws;

    const int total = in_sizes[0];                 // 131072 * 169

    // Long-lived blocks: ~5.3 iterations/thread at B=131072.
    int grid = 2048;
    const int work = (total / 8 + BLOCK - 1) / BLOCK;
    if (grid > work) grid = work > 0 ? work : 1;
    if ((size_t)grid * sizeof(float) > ws_size) grid = (int)(ws_size / sizeof(float));
    if (grid < 1) grid = 1;

    fused_residual_v10<<<grid, BLOCK, 0, stream>>>(T, H, F, Tenv, K, E, partials,
                                                   total);

    const float inv_total = 1.0f / (float)total;
    finalize_kernel<<<1, BLOCK, 0, stream>>>(partials, grid, out, inv_total);
}